// Round 6
// baseline (292.434 us; speedup 1.0000x reference)
//
#include <hip/hip_runtime.h>

#define BATCH 16384
#define KDIM  8192
#define ODIM  32
#define THREADS 512
#define NWAVE 8
#define KT    256               // k per tile (1 KB per row -> long HBM bursts)
#define NT    (KDIM / KT)       // 32 tiles
#define C4    (KT / 4)          // 64 float4 chunks per row per tile

// direct global->LDS DMA, 16B per lane; dest = wave-uniform base + lane*16
__device__ __forceinline__ void gload16(const float* g, float4* l) {
    __builtin_amdgcn_global_load_lds(
        (const __attribute__((address_space(1))) void*)g,
        (__attribute__((address_space(3))) void*)l, 16, 0, 0);
}

// ---------------------------------------------------------------------------
// Prep 1: bwT[k][o] = sign(w[o][k]) as +-1.0f/0, + per-block partial sum |w|
// ---------------------------------------------------------------------------
__global__ void prep_kernel(const float* __restrict__ w,
                            float* __restrict__ bwT,
                            float* __restrict__ partial) {
    int idx = blockIdx.x * 256 + threadIdx.x;     // coalesced over 32*8192
    int o = idx >> 13;
    int k = idx & (KDIM - 1);
    float v = w[idx];
    float s = (v > 0.f) ? 1.f : ((v < 0.f) ? -1.f : 0.f);
    bwT[(size_t)k * ODIM + o] = s;

    float a = fabsf(v);
    #pragma unroll
    for (int off = 32; off; off >>= 1) a += __shfl_down(a, off, 64);
    __shared__ float red[4];
    int lane = threadIdx.x & 63, wv = threadIdx.x >> 6;
    if (lane == 0) red[wv] = a;
    __syncthreads();
    if (threadIdx.x == 0)
        partial[blockIdx.x] = (red[0] + red[1]) + (red[2] + red[3]);
}

__global__ void scale_kernel(const float* __restrict__ partial,
                             float* __restrict__ scale) {
    int t = threadIdx.x;   // 256 threads
    float a = (partial[t] + partial[t + 256]) + (partial[t + 512] + partial[t + 768]);
    #pragma unroll
    for (int off = 32; off; off >>= 1) a += __shfl_down(a, off, 64);
    __shared__ float red[4];
    if ((t & 63) == 0) red[t >> 6] = a;
    __syncthreads();
    if (t == 0)
        scale[0] = ((red[0] + red[1]) + (red[2] + red[3])) / (float)(ODIM * KDIM);
}

// ---------------------------------------------------------------------------
// Main: 256 blocks x 512 threads (1 block/CU). Tile = 64 rows x 256 k (64 KB),
// double-buffered (128 KB LDS). Each global_load_lds reads 1 KB CONTIGUOUS of
// one row (long HBM bursts). Source XOR-swizzle (chunk = lane ^ (row&7)) with
// linear LDS dest; reads undo it -> conflict-free ds_read_b128.
// Counted vmcnt(8): next tile's DMA stays in flight across barriers.
// lane = row -> weights wave-uniform (readfirstlane) -> scalar s_load.
// ---------------------------------------------------------------------------
__global__ __launch_bounds__(THREADS, 2)
void main_kernel(const float* __restrict__ x,
                 const float* __restrict__ bwT,
                 const float* __restrict__ scale_p,
                 float* __restrict__ out) {
    __shared__ union {
        float4 buf[2][64][C4];          // 2 x 64 KB = 128 KB
        float  part[NWAVE][ODIM][65];   // cross-wave reduce staging (65 KB)
    } sm;

    const int tid  = threadIdx.x;
    const int wv   = __builtin_amdgcn_readfirstlane(tid >> 6);  // MUST be SGPR
    const int lane = tid & 63;
    const size_t rowbase = (size_t)blockIdx.x * 64;

    // this wave stages rows 8*wv + i; lane reads float4-chunk (lane ^ i)
    const float* gp[8];
    #pragma unroll
    for (int i = 0; i < 8; ++i)
        gp[i] = x + (rowbase + 8 * wv + i) * (size_t)KDIM + 4 * (lane ^ i);

    float acc[ODIM];
    #pragma unroll
    for (int o = 0; o < ODIM; ++o) acc[o] = 0.f;

#define ISSUE(db) do {                                        \
        _Pragma("unroll")                                     \
        for (int i = 0; i < 8; ++i)                           \
            gload16(gp[i], &sm.buf[db][8 * wv + i][0]);       \
        _Pragma("unroll")                                     \
        for (int i = 0; i < 8; ++i) gp[i] += KT;              \
    } while (0)

    ISSUE(0);                       // tile 0 -> buf0 (8 loads in flight)

    const float* wt = bwT + (size_t)wv * 32 * ODIM;   // k = t*KT + wv*32 + ...

    for (int t = 0; t < NT; ++t) {
        if (t + 1 < NT) {
            ISSUE((t + 1) & 1);     // 16 outstanding
            asm volatile("s_waitcnt vmcnt(8)" ::: "memory");   // tile t landed
        } else {
            asm volatile("s_waitcnt vmcnt(0)" ::: "memory");
        }
        __builtin_amdgcn_s_barrier();
        asm volatile("" ::: "memory");

        // lane = row; read this wave's 8 chunks (32 k), undoing the swizzle
        const float4* row = &sm.buf[t & 1][lane][0];
        float4 xc[8];
        #pragma unroll
        for (int j = 0; j < 8; ++j)
            xc[j] = row[(wv * 8 + j) ^ (lane & 7)];

        #pragma unroll
        for (int j = 0; j < 8; ++j) {
            const float xs[4] = {xc[j].x, xc[j].y, xc[j].z, xc[j].w};
            #pragma unroll
            for (int kk = 0; kk < 4; ++kk) {
                const float* __restrict__ wo = wt + (j * 4 + kk) * ODIM;
                #pragma unroll
                for (int o = 0; o < ODIM; ++o)
                    acc[o] = fmaf(xs[kk], wo[o], acc[o]);
            }
        }
        wt += KT * ODIM;

        asm volatile("" ::: "memory");
        __builtin_amdgcn_s_barrier();   // buf[t&1] free for tile t+2's DMA
        asm volatile("" ::: "memory");
    }
#undef ISSUE

    // cross-wave k-reduce + scaled output (deterministic order)
    __syncthreads();
    #pragma unroll
    for (int o = 0; o < ODIM; ++o) sm.part[wv][o][lane] = acc[o];
    __syncthreads();

    const float scl = scale_p[0];
    float* __restrict__ ob = out + rowbase * ODIM;
    #pragma unroll
    for (int it = 0; it < 4; ++it) {
        int j = tid + THREADS * it;       // 0..2047 = r*32 + o, coalesced
        int r = j >> 5, o = j & 31;
        float s = 0.f;
        #pragma unroll
        for (int w = 0; w < NWAVE; ++w) s += sm.part[w][o][r];
        ob[j] = s * scl;
    }
}

// ---------------------------------------------------------------------------
extern "C" void kernel_launch(void* const* d_in, const int* in_sizes, int n_in,
                              void* d_out, int out_size, void* d_ws, size_t ws_size,
                              hipStream_t stream) {
    const float* x = (const float*)d_in[0];
    const float* w = (const float*)d_in[1];
    float* out = (float*)d_out;

    float* wsf     = (float*)d_ws;
    float* partial = wsf;            // 1024 floats
    float* scale   = wsf + 1024;     // 1 float
    float* bwT     = wsf + 2048;     // 262144 floats (1 MiB), [k][o]

    prep_kernel<<<1024, 256, 0, stream>>>(w, bwT, partial);
    scale_kernel<<<1, 256, 0, stream>>>(partial, scale);
    main_kernel<<<BATCH / 64, THREADS, 0, stream>>>(x, bwT, scale, out);
}

// Round 7
// 175.412 us; speedup vs baseline: 1.6671x; 1.6671x over previous
//
#include <hip/hip_runtime.h>

#define BATCH 16384
#define KDIM  8192
#define ODIM  32
#define SK    8                   // split-K across blocks
#define KSLICE (KDIM / SK)        // 1024 k per block
#define NWAVE 4
#define THREADS (NWAVE * 64)
#define KT2   16                  // k per LDS tile
#define NTILE (KSLICE / KT2)      // 64 tiles
#define LP    20                  // padded row stride (floats): conflict-free r/w

// ---------------------------------------------------------------------------
// Prep 1: bwT[k][o] = sign(w[o][k]) as +-1.0f/0, + per-block partial sum |w|
// ---------------------------------------------------------------------------
__global__ void prep_kernel(const float* __restrict__ w,
                            float* __restrict__ bwT,
                            float* __restrict__ partial) {
    int idx = blockIdx.x * 256 + threadIdx.x;     // coalesced over 32*8192
    int o = idx >> 13;
    int k = idx & (KDIM - 1);
    float v = w[idx];
    float s = (v > 0.f) ? 1.f : ((v < 0.f) ? -1.f : 0.f);
    bwT[(size_t)k * ODIM + o] = s;

    float a = fabsf(v);
    #pragma unroll
    for (int off = 32; off; off >>= 1) a += __shfl_down(a, off, 64);
    __shared__ float red[4];
    int lane = threadIdx.x & 63, wv = threadIdx.x >> 6;
    if (lane == 0) red[wv] = a;
    __syncthreads();
    if (threadIdx.x == 0)
        partial[blockIdx.x] = (red[0] + red[1]) + (red[2] + red[3]);
}

__global__ void scale_kernel(const float* __restrict__ partial,
                             float* __restrict__ scale) {
    int t = threadIdx.x;   // 256 threads
    float a = (partial[t] + partial[t + 256]) + (partial[t + 512] + partial[t + 768]);
    #pragma unroll
    for (int off = 32; off; off >>= 1) a += __shfl_down(a, off, 64);
    __shared__ float red[4];
    if ((t & 63) == 0) red[t >> 6] = a;
    __syncthreads();
    if (t == 0)
        scale[0] = ((red[0] + red[1]) + (red[2] + red[3])) / (float)(ODIM * KDIM);
}

// ---------------------------------------------------------------------------
// Main: R2 structure at 2x occupancy. 2048 blocks x 256 thr, 8 blocks/CU
// (32 waves/CU) to interleave per-wave s_load weight-fetch stalls.
// Tile = 64 rows x 16 k (padded [64][20] LDS, conflict-free), double-buffered,
// 1 barrier/tile. lane = row -> weights wave-uniform (readfirstlane) -> s_load.
// Split-K=8 partials, two-phase LDS cross-wave reduce, no atomics.
// ---------------------------------------------------------------------------
__global__ __launch_bounds__(THREADS, 8)
void main_kernel(const float* __restrict__ x,
                 const float* __restrict__ bwT,
                 float* __restrict__ pout) {
    __shared__ union {
        float buf[2][64][LP];     // 10240 B
        float part[2][ODIM][65];  // 16640 B (union -> 16.6 KB total)
    } sm;

    const int tid  = threadIdx.x;
    const int wv   = __builtin_amdgcn_readfirstlane(tid >> 6);  // MUST be SGPR
    const int lane = tid & 63;
    const int kb   = blockIdx.x >> 8;          // 0..7  (same-kb blocks adjacent)
    const int rb   = blockIdx.x & 255;         // 0..255
    const size_t rowbase = (size_t)rb * 64;
    const int kbase = kb * KSLICE;

    // staging: thread t loads float4 at (row = t/4, k4 = t%4)
    const int sr = tid >> 2;
    const int sq = tid & 3;
    const float* __restrict__ xg = x + (rowbase + sr) * (size_t)KDIM + kbase + 4 * sq;

    float acc[ODIM];
    #pragma unroll
    for (int o = 0; o < ODIM; ++o) acc[o] = 0.f;

    // prologue: tile 0 -> buf0
    float4 v = *(const float4*)xg;
    *(float4*)&sm.buf[0][sr][4 * sq] = v;      // 80B row stride, 16B aligned

    const float* wt = bwT + (size_t)(kbase + wv * 4) * ODIM;

    for (int t = 0; t < NTILE; ++t) {
        float4 vn;
        if (t + 1 < NTILE) vn = *(const float4*)(xg + (t + 1) * KT2);

        __syncthreads();   // buf[t&1] fully written; buf[(t+1)&1] free

        // this wave's 4 k's of the tile: one conflict-free ds_read_b128
        const float4 xk = *(const float4*)&sm.buf[t & 1][lane][wv * 4];

        if (t + 1 < NTILE) *(float4*)&sm.buf[(t + 1) & 1][sr][4 * sq] = vn;

        const float xs[4] = {xk.x, xk.y, xk.z, xk.w};
        #pragma unroll
        for (int kk = 0; kk < 4; ++kk) {
            const float* __restrict__ wo = wt + (t * KT2 + kk) * ODIM;
            #pragma unroll
            for (int o = 0; o < ODIM; ++o)
                acc[o] = fmaf(xs[kk], wo[o], acc[o]);
        }
    }

    // two-phase cross-wave reduce (fits 16.6 KB LDS)
    __syncthreads();
    if (wv < 2) {
        #pragma unroll
        for (int o = 0; o < ODIM; ++o) sm.part[wv][o][lane] = acc[o];
    }
    __syncthreads();
    if (wv >= 2) {
        #pragma unroll
        for (int o = 0; o < ODIM; ++o) sm.part[wv - 2][o][lane] += acc[o];
    }
    __syncthreads();

    float* __restrict__ pb = pout + ((size_t)kb * BATCH + rowbase) * ODIM;
    #pragma unroll
    for (int i = 0; i < 8; ++i) {
        int j = tid + THREADS * i;        // j = r*32 + o, fully coalesced
        int r = j >> 5, o = j & 31;
        pb[j] = sm.part[0][o][r] + sm.part[1][o][r];
    }
}

// ---------------------------------------------------------------------------
// Final: out = (sum of 8 split-K partials) * scale
// ---------------------------------------------------------------------------
__global__ void reduce_kernel(const float* __restrict__ pout,
                              const float* __restrict__ scale_p,
                              float* __restrict__ out) {
    const int STRIDE = BATCH * ODIM / 4;          // float4 per split slice
    int i = blockIdx.x * 256 + threadIdx.x;       // grid 512 x 256
    const float s = scale_p[0];
    const float4* p = (const float4*)pout;
    float4 r = p[i];
    #pragma unroll
    for (int k = 1; k < SK; ++k) {
        float4 a = p[i + k * STRIDE];
        r.x += a.x; r.y += a.y; r.z += a.z; r.w += a.w;
    }
    r.x *= s; r.y *= s; r.z *= s; r.w *= s;
    ((float4*)out)[i] = r;
}

// ---------------------------------------------------------------------------
extern "C" void kernel_launch(void* const* d_in, const int* in_sizes, int n_in,
                              void* d_out, int out_size, void* d_ws, size_t ws_size,
                              hipStream_t stream) {
    const float* x = (const float*)d_in[0];
    const float* w = (const float*)d_in[1];
    float* out = (float*)d_out;

    float* wsf     = (float*)d_ws;
    float* partial = wsf;                       // 1024 floats
    float* scale   = wsf + 1024;                // 1 float
    float* bwT     = wsf + 2048;                // 262144 floats (1 MiB), [k][o]
    float* pout    = wsf + 2048 + ODIM * KDIM;  // SK * 524288 floats (16 MiB)

    prep_kernel<<<1024, 256, 0, stream>>>(w, bwT, partial);
    scale_kernel<<<1, 256, 0, stream>>>(partial, scale);
    main_kernel<<<256 * SK, THREADS, 0, stream>>>(x, bwT, pout);
    reduce_kernel<<<BATCH * ODIM / 4 / 256, 256, 0, stream>>>(pout, scale, out);
}